// Round 15
// baseline (255.358 us; speedup 1.0000x reference)
//
#include <hip/hip_runtime.h>
#include <hip/hip_fp16.h>
#include <math.h>

#define NN 50000
#define EE 800000
#define TOT_EDGES (EE + NN)   // with self loops
#define FD 3
#define C 64
#define FC 512
#define NODES_PER_GRAPH 5000
#define NUM_GRAPHS 10
#define POOL_CHUNKS 40        // 5000 / 125
#define POOL_NODES_PER_CHUNK 125
#define NEG_SLOPE 0.2f

#define SCAN_BLK 1024
#define SCAN_GRID ((NN + SCAN_BLK - 1) / SCAN_BLK)   // 49

#define HC_BLOCKS 1024        // layer-1 scalar hcompute: 4096 waves

#define STRIPES (NN / 16)     // 3125 MFMA row-stripes (50000 % 16 == 0)
#define MFMA_BLOCKS ((STRIPES + 3) / 4)

#define HALF_NN (NN / 2)      // dual-node aggregate: wave handles n and n+HALF_NN
#define AGG_BLOCKS ((HALF_NN + 3) / 4)   // 6250

// XCD-range-partitioned CSR build (see R5): keeps each XCD's scatter footprint
// L2-resident so line writes coalesce in L2 instead of 64B-per-edge HBM writebacks.
#define NPART 8
#define PART_NODES ((NN + NPART - 1) / NPART)        // 6250
#define CSR_EPT 8
#define CSR_CHUNK (256 * CSR_EPT)                    // 2048 edges / block
#define CSR_CHUNKS ((TOT_EDGES + CSR_CHUNK - 1) / CSR_CHUNK)

typedef _Float16 f16x8 __attribute__((ext_vector_type(8)));
typedef float f32x4 __attribute__((ext_vector_type(4)));

// ---------------- CSR build ----------------

__global__ void k_count_part(const int* __restrict__ dst, int* __restrict__ counts) {
    int part = blockIdx.x & (NPART - 1);
    int chunk = blockIdx.x >> 3;
    int lo = part * PART_NODES, hi = lo + PART_NODES;
    int base = chunk * CSR_CHUNK + threadIdx.x;
#pragma unroll
    for (int e = 0; e < CSR_EPT; ++e) {
        int i = base + e * 256;
        if (i < TOT_EDGES) {
            int d = (i < EE) ? dst[i] : (i - EE);
            if (d >= lo && d < hi) atomicAdd(&counts[d], 1);
        }
    }
}

// stage 1: per-block LDS scan (exclusive within block) + block sums
__global__ void k_scan1(const int* __restrict__ counts, int* __restrict__ offsets,
                        int* __restrict__ blocksums) {
    int tid = threadIdx.x, blk = blockIdx.x;
    int i = blk * SCAN_BLK + tid;
    int v = (i < NN) ? counts[i] : 0;
    __shared__ int buf[SCAN_BLK];
    buf[tid] = v;
    __syncthreads();
    for (int off = 1; off < SCAN_BLK; off <<= 1) {
        int t = (tid >= off) ? buf[tid - off] : 0;
        __syncthreads();
        buf[tid] += t;
        __syncthreads();
    }
    if (i < NN) offsets[i] = buf[tid] - v;   // exclusive
    if (tid == SCAN_BLK - 1) blocksums[blk] = buf[tid];
}

// stage 2: serial scan of 49 block sums (one lane)
__global__ void k_scan2(int* __restrict__ blocksums, int* __restrict__ offsets) {
    if (threadIdx.x == 0) {
        int run = 0;
        for (int b = 0; b < SCAN_GRID; ++b) {
            int v = blocksums[b];
            blocksums[b] = run;
            run += v;
        }
        offsets[NN] = run;   // = TOT_EDGES
    }
}

// stage 3: add block base, emit cursors
__global__ void k_scan3(int* __restrict__ offsets, int* __restrict__ cursors,
                        const int* __restrict__ blocksums) {
    int tid = threadIdx.x, blk = blockIdx.x;
    int i = blk * SCAN_BLK + tid;
    if (i < NN) {
        int o = offsets[i] + blocksums[blk];
        offsets[i] = o;
        cursors[i] = o;
    }
}

__global__ void k_scatter_part(const int* __restrict__ src, const int* __restrict__ dst,
                               int* __restrict__ cursors, int* __restrict__ ssrc) {
    int part = blockIdx.x & (NPART - 1);
    int chunk = blockIdx.x >> 3;
    int lo = part * PART_NODES, hi = lo + PART_NODES;
    int base = chunk * CSR_CHUNK + threadIdx.x;
#pragma unroll
    for (int e = 0; e < CSR_EPT; ++e) {
        int i = base + e * 256;
        if (i < TOT_EDGES) {
            int d = (i < EE) ? dst[i] : (i - EE);
            if (d >= lo && d < hi) {
                int s = (i < EE) ? src[i] : d;
                int idx = atomicAdd(&cursors[d], 1);
                ssrc[idx] = s;
            }
        }
    }
}

// ---------------- W fragment packing (for MFMA projections) ----------------
// wpack layout: [layer(3)][frag(8)][lane(64)][j(8)] halves; frag f = t*2+h.
// B-fragment mapping (K=32 x N=16): lane l -> col = l&15, k = (l>>4)*8 + j.
__global__ void k_wpack(const float* __restrict__ Wh, const float* __restrict__ W2,
                        __half* __restrict__ wpack) {
    int tid = blockIdx.x * blockDim.x + threadIdx.x;
    if (tid >= 3 * 8 * 64) return;
    int l = tid & 63, f = (tid >> 6) & 7, layer = tid >> 9;
    const float* W = (layer == 0) ? Wh : (layer == 1) ? (Wh + 4096) : W2;
    int t = f >> 1, h = f & 1;
#pragma unroll
    for (int j = 0; j < 8; ++j) {
        float w = W[(h * 32 + (l >> 4) * 8 + j) * 64 + (t * 16 + (l & 15))];
        wpack[(size_t)tid * 8 + j] = __float2half(w);
    }
}

// ---------------- GAT layer kernels ----------------

// Layer-1 projection: h = x @ W1 (FD=3 -> C); es/ed. Scalar path (K=3).
__global__ void k_hcompute_f3(const float* __restrict__ x,
                              const float* __restrict__ W,
                              const float* __restrict__ a_s, const float* __restrict__ a_d,
                              __half* __restrict__ h, float* __restrict__ es,
                              float* __restrict__ ed, int nwaves_total) {
    int lane = threadIdx.x & 63;
    int wid = (blockIdx.x * blockDim.x + threadIdx.x) >> 6;

    float wcol[FD];
#pragma unroll
    for (int k = 0; k < FD; ++k) wcol[k] = W[k * 64 + lane];
    float asl = a_s[lane], adl = a_d[lane];

    for (int n = wid; n < NN; n += nwaves_total) {
        int nu = __builtin_amdgcn_readfirstlane(n);
        const float* xrow = x + (size_t)nu * FD;
        float acc = 0.f;
#pragma unroll
        for (int k = 0; k < FD; ++k) acc = fmaf(xrow[k], wcol[k], acc);
        h[(size_t)nu * 64 + lane] = __float2half(acc);
        float vs = acc * asl;
        float vd = acc * adl;
        for (int w = 32; w >= 1; w >>= 1) {
            vs += __shfl_xor(vs, w);
            vd += __shfl_xor(vd, w);
        }
        if (lane == 0) { es[nu] = vs; ed[nu] = vd; }
    }
}

// Hidden/final projection as MFMA GEMM (R13, verified): one wave = 16x64 stripe,
// 8x mfma_f32_16x16x32_f16. es/ed folded via per-tile scale + 16-lane butterfly.
__global__ void k_hc_mfma(const __half* __restrict__ X,
                          const __half* __restrict__ wpack,   // this layer's 8 frags
                          const float* __restrict__ a_s, const float* __restrict__ a_d,
                          __half* __restrict__ H, float* __restrict__ es,
                          float* __restrict__ ed) {
    int lane = threadIdx.x & 63;
    int stripe = (blockIdx.x * blockDim.x + threadIdx.x) >> 6;
    if (stripe >= STRIPES) return;
    int rowbase = stripe * 16;
    int lr = lane & 15, lg = lane >> 4;

    f16x8 b[8];
    const float4* wp = (const float4*)wpack;
#pragma unroll
    for (int f = 0; f < 8; ++f) {
        float4 raw = wp[f * 64 + lane];
        b[f] = *(const f16x8*)&raw;
    }
    const __half* xrow = X + (size_t)(rowbase + lr) * 64 + lg * 8;
    float4 a0raw = *(const float4*)xrow;
    float4 a1raw = *(const float4*)(xrow + 32);
    f16x8 a0 = *(const f16x8*)&a0raw;
    f16x8 a1 = *(const f16x8*)&a1raw;

    float esa[4] = {0.f, 0.f, 0.f, 0.f};
    float eda[4] = {0.f, 0.f, 0.f, 0.f};
#pragma unroll
    for (int t = 0; t < 4; ++t) {
        f32x4 acc = {0.f, 0.f, 0.f, 0.f};
        acc = __builtin_amdgcn_mfma_f32_16x16x32_f16(a0, b[t * 2], acc, 0, 0, 0);
        acc = __builtin_amdgcn_mfma_f32_16x16x32_f16(a1, b[t * 2 + 1], acc, 0, 0, 0);
        float asv = a_s[t * 16 + lr];
        float adv = a_d[t * 16 + lr];
#pragma unroll
        for (int r = 0; r < 4; ++r) {
            float v = acc[r];
            H[(size_t)(rowbase + lg * 4 + r) * 64 + t * 16 + lr] = __float2half(v);
            esa[r] = fmaf(v, asv, esa[r]);
            eda[r] = fmaf(v, adv, eda[r]);
        }
    }
#pragma unroll
    for (int w = 1; w <= 8; w <<= 1) {
#pragma unroll
        for (int r = 0; r < 4; ++r) {
            esa[r] += __shfl_xor(esa[r], w);
            eda[r] += __shfl_xor(eda[r], w);
        }
    }
    if (lr == 0) {
#pragma unroll
        for (int r = 0; r < 4; ++r) {
            es[rowbase + lg * 4 + r] = esa[r];
            ed[rowbase + lg * 4 + r] = eda[r];
        }
    }
}

// Dual-node aggregate (R15): one wave processes TWO dst nodes (n, n+HALF_NN),
// interleaved for 2x memory-level parallelism on the latency-bound gather
// chains. Phase A: edge-per-lane p for both nodes (2 independent es-gather
// chains in flight). Phase B: 4 independent 16B h-row gathers per sub-iter
// (2 per node). Tail lanes predicated (p=0 -> fma adds 0). Per-node summation
// order identical to R14 -> bitwise-identical output.
template<int HIDDEN>
__global__ void k_aggregate(const __half* __restrict__ h,
                            const float* __restrict__ es, const float* __restrict__ ed,
                            const int* __restrict__ offsets, const int* __restrict__ ssrc,
                            const float* __restrict__ bias,
                            __half* __restrict__ outH, float* __restrict__ outF) {
    int wid = (blockIdx.x * blockDim.x + threadIdx.x) >> 6;
    int lane = threadIdx.x & 63;
    if (wid >= HALF_NN) return;
    int n0 = wid, n1 = wid + HALF_NN;

    int beg0 = offsets[n0], end0 = offsets[n0 + 1];
    int beg1 = offsets[n1], end1 = offsets[n1 + 1];
    int nc0 = end0 - beg0, nc1 = end1 - beg1;
    float ed0 = ed[n0], ed1 = ed[n1];

    int grp = lane >> 3;        // 0..7 : which edge of the group
    int c   = lane & 7;         // channel block: halves [8c, 8c+8)
    float s0 = 0.f, s1 = 0.f;
    float acc0[8], acc1[8];
#pragma unroll
    for (int i = 0; i < 8; ++i) { acc0[i] = 0.f; acc1[i] = 0.f; }

    for (int ch = 0; ch * 64 < nc0 || ch * 64 < nc1; ++ch) {
        int o = ch * 64 + lane;
        bool a0 = o < nc0, a1 = o < nc1;
        int sj0A = 0, sj1A = 0;
        if (a0) sj0A = ssrc[beg0 + o];
        if (a1) sj1A = ssrc[beg1 + o];
        float ev0 = es[sj0A];   // both gathers issued before use
        float ev1 = es[sj1A];
        float p0 = 0.f, p1 = 0.f;
        if (a0) { float e = ev0 + ed0; e = (e > 0.f) ? e : NEG_SLOPE * e; p0 = __expf(e); }
        if (a1) { float e = ev1 + ed1; e = (e > 0.f) ? e : NEG_SLOPE * e; p1 = __expf(e); }
        s0 += p0; s1 += p1;

        int cnt0 = nc0 - ch * 64; cnt0 = cnt0 < 0 ? 0 : (cnt0 > 64 ? 64 : cnt0);
        int cnt1 = nc1 - ch * 64; cnt1 = cnt1 < 0 ? 0 : (cnt1 > 64 ? 64 : cnt1);
        int cmax = cnt0 > cnt1 ? cnt0 : cnt1;
        for (int sub = 0; sub * 16 < cmax; ++sub) {
            int ea = sub * 16 + grp;
            int eb = sub * 16 + 8 + grp;
            float p0a = __shfl(p0, ea), p0b = __shfl(p0, eb);
            float p1a = __shfl(p1, ea), p1b = __shfl(p1, eb);
            int s0a = __shfl(sj0A, ea), s0b = __shfl(sj0A, eb);
            int s1a = __shfl(sj1A, ea), s1b = __shfl(sj1A, eb);
            // 4 independent row gathers in flight
            float4 r0a = *(const float4*)&h[(size_t)s0a * 64 + c * 8];
            float4 r0b = *(const float4*)&h[(size_t)s0b * 64 + c * 8];
            float4 r1a = *(const float4*)&h[(size_t)s1a * 64 + c * 8];
            float4 r1b = *(const float4*)&h[(size_t)s1b * 64 + c * 8];
            const __half2* h0a = (const __half2*)&r0a;
            const __half2* h0b = (const __half2*)&r0b;
            const __half2* h1a = (const __half2*)&r1a;
            const __half2* h1b = (const __half2*)&r1b;
#pragma unroll
            for (int q = 0; q < 4; ++q) {
                float2 f0a = __half22float2(h0a[q]);
                float2 f0b = __half22float2(h0b[q]);
                acc0[2 * q]     = fmaf(p0a, f0a.x, acc0[2 * q]);
                acc0[2 * q + 1] = fmaf(p0a, f0a.y, acc0[2 * q + 1]);
                acc0[2 * q]     = fmaf(p0b, f0b.x, acc0[2 * q]);
                acc0[2 * q + 1] = fmaf(p0b, f0b.y, acc0[2 * q + 1]);
                float2 f1a = __half22float2(h1a[q]);
                float2 f1b = __half22float2(h1b[q]);
                acc1[2 * q]     = fmaf(p1a, f1a.x, acc1[2 * q]);
                acc1[2 * q + 1] = fmaf(p1a, f1a.y, acc1[2 * q + 1]);
                acc1[2 * q]     = fmaf(p1b, f1b.x, acc1[2 * q]);
                acc1[2 * q + 1] = fmaf(p1b, f1b.y, acc1[2 * q + 1]);
            }
        }
    }
    // s: full 64-lane butterfly; acc: reduce across the 8 edge-groups
#pragma unroll
    for (int w = 32; w >= 1; w >>= 1) { s0 += __shfl_xor(s0, w); s1 += __shfl_xor(s1, w); }
#pragma unroll
    for (int w = 8; w <= 32; w <<= 1) {
#pragma unroll
        for (int i = 0; i < 8; ++i) {
            acc0[i] += __shfl_xor(acc0[i], w);
            acc1[i] += __shfl_xor(acc1[i], w);
        }
    }
    if (grp == 0) {
        float inv0 = 1.0f / s0, inv1 = 1.0f / s1;
        float v0[8], v1[8];
#pragma unroll
        for (int i = 0; i < 8; ++i) {
            float b = bias[c * 8 + i];
            v0[i] = acc0[i] * inv0 + b;
            v1[i] = acc1[i] * inv1 + b;
            if (HIDDEN) { v0[i] = fmaxf(v0[i], 0.f); v1[i] = fmaxf(v1[i], 0.f); }
        }
        if (HIDDEN) {
            __half2 h0[4], h1[4];
#pragma unroll
            for (int q = 0; q < 4; ++q) {
                h0[q] = __floats2half2_rn(v0[2 * q], v0[2 * q + 1]);
                h1[q] = __floats2half2_rn(v1[2 * q], v1[2 * q + 1]);
            }
            *(float4*)&outH[(size_t)n0 * 64 + c * 8] = *(float4*)h0;   // 16B
            *(float4*)&outH[(size_t)n1 * 64 + c * 8] = *(float4*)h1;
        } else {
            *(float4*)&outF[(size_t)n0 * 64 + c * 8]     = make_float4(v0[0], v0[1], v0[2], v0[3]);
            *(float4*)&outF[(size_t)n0 * 64 + c * 8 + 4] = make_float4(v0[4], v0[5], v0[6], v0[7]);
            *(float4*)&outF[(size_t)n1 * 64 + c * 8]     = make_float4(v1[0], v1[1], v1[2], v1[3]);
            *(float4*)&outF[(size_t)n1 * 64 + c * 8 + 4] = make_float4(v1[4], v1[5], v1[6], v1[7]);
        }
    }
}

// ---------------- epilogue ----------------

__global__ void k_pool1(const float* __restrict__ h, float* __restrict__ partial) {
    int blk = blockIdx.x;
    int g = blk / POOL_CHUNKS, c = blk % POOL_CHUNKS;
    int wave = threadIdx.x >> 6, lane = threadIdx.x & 63;
    int base = g * NODES_PER_GRAPH + c * POOL_NODES_PER_CHUNK;
    float acc = 0.f;
    for (int i = wave; i < POOL_NODES_PER_CHUNK; i += 4)
        acc += h[(size_t)(base + i) * 64 + lane];
    __shared__ float buf[4][64];
    buf[wave][lane] = acc;
    __syncthreads();
    if (wave == 0)
        partial[blk * 64 + lane] = buf[0][lane] + buf[1][lane] + buf[2][lane] + buf[3][lane];
}

// fused pool-stage-2 + value head: 10 blocks x 512 threads.
__global__ void k_pool2_value(const float* __restrict__ partial,
                              const float* __restrict__ Wv1, const float* __restrict__ bv1,
                              const float* __restrict__ Wv2, const float* __restrict__ bv2,
                              float* __restrict__ pooled, float* __restrict__ value) {
    int g = blockIdx.x;
    int j = threadIdx.x;   // 512
    __shared__ float pl[64];
    if (j < 64) {
        float a = 0.f;
        for (int cc = 0; cc < POOL_CHUNKS; ++cc)
            a += partial[(g * POOL_CHUNKS + cc) * 64 + j];
        a *= (1.0f / NODES_PER_GRAPH);
        pooled[g * 64 + j] = a;
        pl[j] = a;
    }
    __syncthreads();
    float acc = bv1[j];
    for (int cc = 0; cc < 64; ++cc) acc += pl[cc] * Wv1[cc * 512 + j];
    acc = fmaxf(acc, 0.f);
    float t = acc * Wv2[j];
    for (int w = 32; w >= 1; w >>= 1) t += __shfl_xor(t, w);
    __shared__ float red[8];
    int wave = j >> 6, lane = j & 63;
    if (lane == 0) red[wave] = t;
    __syncthreads();
    if (j == 0) {
        float v = 0.f;
        for (int w = 0; w < 8; ++w) v += red[w];
        value[g] = v + bv2[0];
    }
}

// ---------------- launcher ----------------

extern "C" void kernel_launch(void* const* d_in, const int* in_sizes, int n_in,
                              void* d_out, int out_size, void* d_ws, size_t ws_size,
                              hipStream_t stream) {
    const float* x   = (const float*)d_in[0];
    const int*   ei  = (const int*)d_in[1];     // (2, E): row0=src, row1=dst
    const float* W1  = (const float*)d_in[2];
    const float* as1 = (const float*)d_in[3];
    const float* ad1 = (const float*)d_in[4];
    const float* b1  = (const float*)d_in[5];
    const float* Wh  = (const float*)d_in[6];   // (2,64,64)
    const float* ash = (const float*)d_in[7];
    const float* adh = (const float*)d_in[8];
    const float* bh  = (const float*)d_in[9];
    const float* W2  = (const float*)d_in[10];
    const float* as2 = (const float*)d_in[11];
    const float* ad2 = (const float*)d_in[12];
    const float* b2  = (const float*)d_in[13];
    const float* Wv1 = (const float*)d_in[14];
    const float* bv1 = (const float*)d_in[15];
    const float* Wv2 = (const float*)d_in[16];
    const float* bv2 = (const float*)d_in[17];

    const int* e_src = ei;
    const int* e_dst = ei + EE;

    // workspace carve-up (256B aligned)
    char* p = (char*)d_ws;
    auto carve = [&](size_t bytes) {
        char* r = p;
        p += (bytes + 255) & ~(size_t)255;
        return r;
    };
    int*    counts    = (int*)carve(NN * 4);
    int*    offsets   = (int*)carve((NN + 1) * 4);
    int*    cursors   = (int*)carve(NN * 4);
    int*    ssrc      = (int*)carve(TOT_EDGES * 4);
    int*    blocksums = (int*)carve(SCAN_GRID * 4);
    __half* wpack     = (__half*)carve(3 * 8 * 64 * 8 * 2);    // packed W fragments
    __half* bufH      = (__half*)carve((size_t)NN * 64 * 2);   // fp16 gather table
    __half* bufB16    = (__half*)carve((size_t)NN * 64 * 2);   // fp16 layer boundary
    float*  es        = (float*)carve(NN * 4);
    float*  ed        = (float*)carve(NN * 4);
    float*  partial   = (float*)carve((size_t)NUM_GRAPHS * POOL_CHUNKS * 64 * 4);

    float* out_h      = (float*)d_out;                 // [N, 64]
    float* out_pooled = out_h + (size_t)NN * 64;       // [10, 64]
    float* out_value  = out_pooled + NUM_GRAPHS * 64;  // [10]

    // CSR build (reused by all 4 layers) + W packing
    hipMemsetAsync(counts, 0, NN * 4, stream);
    k_count_part<<<NPART * CSR_CHUNKS, 256, 0, stream>>>(e_dst, counts);
    k_scan1<<<SCAN_GRID, SCAN_BLK, 0, stream>>>(counts, offsets, blocksums);
    k_scan2<<<1, 64, 0, stream>>>(blocksums, offsets);
    k_scan3<<<SCAN_GRID, SCAN_BLK, 0, stream>>>(offsets, cursors, blocksums);
    k_scatter_part<<<NPART * CSR_CHUNKS, 256, 0, stream>>>(e_src, e_dst, cursors, ssrc);
    k_wpack<<<6, 256, 0, stream>>>(Wh, W2, wpack);

    const int HC_WAVES = HC_BLOCKS * 256 / 64; // 4096
    const int WPL = 8 * 64 * 8;                // wpack halves per layer

    // layer 1: FD -> C (scalar), relu; boundary buffer is fp16
    k_hcompute_f3<<<HC_BLOCKS, 256, 0, stream>>>(x, W1, as1, ad1, bufH, es, ed, HC_WAVES);
    k_aggregate<1><<<AGG_BLOCKS, 256, 0, stream>>>(bufH, es, ed, offsets, ssrc, b1, bufB16, nullptr);

    // hidden layers: C -> C via MFMA, relu in aggregate
    for (int i = 0; i < 2; ++i) {
        k_hc_mfma<<<MFMA_BLOCKS, 256, 0, stream>>>(bufB16, wpack + i * WPL,
                                                   ash + i * 64, adh + i * 64,
                                                   bufH, es, ed);
        k_aggregate<1><<<AGG_BLOCKS, 256, 0, stream>>>(bufH, es, ed, offsets, ssrc, bh + i * 64,
                                                       bufB16, nullptr);
    }

    // layer 4: C -> OUT via MFMA, no relu, write straight to d_out (fp32)
    k_hc_mfma<<<MFMA_BLOCKS, 256, 0, stream>>>(bufB16, wpack + 2 * WPL, as2, ad2,
                                               bufH, es, ed);
    k_aggregate<0><<<AGG_BLOCKS, 256, 0, stream>>>(bufH, es, ed, offsets, ssrc, b2, nullptr, out_h);

    // pooling + value head
    k_pool1<<<NUM_GRAPHS * POOL_CHUNKS, 256, 0, stream>>>(out_h, partial);
    k_pool2_value<<<NUM_GRAPHS, 512, 0, stream>>>(partial, Wv1, bv1, Wv2, bv2,
                                                  out_pooled, out_value);
}

// Round 16
// 251.740 us; speedup vs baseline: 1.0144x; 1.0144x over previous
//
#include <hip/hip_runtime.h>
#include <hip/hip_fp16.h>
#include <math.h>

#define NN 50000
#define EE 800000
#define TOT_EDGES (EE + NN)   // with self loops
#define FD 3
#define C 64
#define FC 512
#define NODES_PER_GRAPH 5000
#define NUM_GRAPHS 10
#define POOL_CHUNKS 40        // 5000 / 125
#define POOL_NODES_PER_CHUNK 125
#define NEG_SLOPE 0.2f

#define SCAN_BLK 1024
#define SCAN_GRID ((NN + SCAN_BLK - 1) / SCAN_BLK)   // 49

#define HC_BLOCKS 1024        // layer-1 scalar hcompute: 4096 waves

#define STRIPES (NN / 16)     // 3125 MFMA row-stripes (50000 % 16 == 0)
#define MFMA_BLOCKS ((STRIPES + 3) / 4)

// XCD-range-partitioned CSR build (see R5): keeps each XCD's scatter footprint
// L2-resident so line writes coalesce in L2 instead of 64B-per-edge HBM writebacks.
#define NPART 8
#define PART_NODES ((NN + NPART - 1) / NPART)        // 6250
#define CSR_EPT 8
#define CSR_CHUNK (256 * CSR_EPT)                    // 2048 edges / block
#define CSR_CHUNKS ((TOT_EDGES + CSR_CHUNK - 1) / CSR_CHUNK)

typedef _Float16 f16x8 __attribute__((ext_vector_type(8)));
typedef float f32x4 __attribute__((ext_vector_type(4)));

// ---------------- CSR build ----------------

__global__ void k_count_part(const int* __restrict__ dst, int* __restrict__ counts) {
    int part = blockIdx.x & (NPART - 1);
    int chunk = blockIdx.x >> 3;
    int lo = part * PART_NODES, hi = lo + PART_NODES;
    int base = chunk * CSR_CHUNK + threadIdx.x;
#pragma unroll
    for (int e = 0; e < CSR_EPT; ++e) {
        int i = base + e * 256;
        if (i < TOT_EDGES) {
            int d = (i < EE) ? dst[i] : (i - EE);
            if (d >= lo && d < hi) atomicAdd(&counts[d], 1);
        }
    }
}

// stage 1: per-block LDS scan (exclusive within block) + block sums
__global__ void k_scan1(const int* __restrict__ counts, int* __restrict__ offsets,
                        int* __restrict__ blocksums) {
    int tid = threadIdx.x, blk = blockIdx.x;
    int i = blk * SCAN_BLK + tid;
    int v = (i < NN) ? counts[i] : 0;
    __shared__ int buf[SCAN_BLK];
    buf[tid] = v;
    __syncthreads();
    for (int off = 1; off < SCAN_BLK; off <<= 1) {
        int t = (tid >= off) ? buf[tid - off] : 0;
        __syncthreads();
        buf[tid] += t;
        __syncthreads();
    }
    if (i < NN) offsets[i] = buf[tid] - v;   // exclusive
    if (tid == SCAN_BLK - 1) blocksums[blk] = buf[tid];
}

// stage 2: serial scan of 49 block sums (one lane)
__global__ void k_scan2(int* __restrict__ blocksums, int* __restrict__ offsets) {
    if (threadIdx.x == 0) {
        int run = 0;
        for (int b = 0; b < SCAN_GRID; ++b) {
            int v = blocksums[b];
            blocksums[b] = run;
            run += v;
        }
        offsets[NN] = run;   // = TOT_EDGES
    }
}

// stage 3: add block base, emit cursors
__global__ void k_scan3(int* __restrict__ offsets, int* __restrict__ cursors,
                        const int* __restrict__ blocksums) {
    int tid = threadIdx.x, blk = blockIdx.x;
    int i = blk * SCAN_BLK + tid;
    if (i < NN) {
        int o = offsets[i] + blocksums[blk];
        offsets[i] = o;
        cursors[i] = o;
    }
}

__global__ void k_scatter_part(const int* __restrict__ src, const int* __restrict__ dst,
                               int* __restrict__ cursors, int* __restrict__ ssrc) {
    int part = blockIdx.x & (NPART - 1);
    int chunk = blockIdx.x >> 3;
    int lo = part * PART_NODES, hi = lo + PART_NODES;
    int base = chunk * CSR_CHUNK + threadIdx.x;
#pragma unroll
    for (int e = 0; e < CSR_EPT; ++e) {
        int i = base + e * 256;
        if (i < TOT_EDGES) {
            int d = (i < EE) ? dst[i] : (i - EE);
            if (d >= lo && d < hi) {
                int s = (i < EE) ? src[i] : d;
                int idx = atomicAdd(&cursors[d], 1);
                ssrc[idx] = s;
            }
        }
    }
}

// ---------------- W fragment packing (for MFMA projections) ----------------
// wpack layout: [layer(3)][frag(8)][lane(64)][j(8)] halves; frag f = t*2+h.
// B-fragment mapping (K=32 x N=16): lane l -> col = l&15, k = (l>>4)*8 + j.
__global__ void k_wpack(const float* __restrict__ Wh, const float* __restrict__ W2,
                        __half* __restrict__ wpack) {
    int tid = blockIdx.x * blockDim.x + threadIdx.x;
    if (tid >= 3 * 8 * 64) return;
    int l = tid & 63, f = (tid >> 6) & 7, layer = tid >> 9;
    const float* W = (layer == 0) ? Wh : (layer == 1) ? (Wh + 4096) : W2;
    int t = f >> 1, h = f & 1;
#pragma unroll
    for (int j = 0; j < 8; ++j) {
        float w = W[(h * 32 + (l >> 4) * 8 + j) * 64 + (t * 16 + (l & 15))];
        wpack[(size_t)tid * 8 + j] = __float2half(w);
    }
}

// ---------------- GAT layer kernels ----------------

// Layer-1 projection: h = x @ W1 (FD=3 -> C); es/ed. Scalar path (K=3).
__global__ void k_hcompute_f3(const float* __restrict__ x,
                              const float* __restrict__ W,
                              const float* __restrict__ a_s, const float* __restrict__ a_d,
                              __half* __restrict__ h, float* __restrict__ es,
                              float* __restrict__ ed, int nwaves_total) {
    int lane = threadIdx.x & 63;
    int wid = (blockIdx.x * blockDim.x + threadIdx.x) >> 6;

    float wcol[FD];
#pragma unroll
    for (int k = 0; k < FD; ++k) wcol[k] = W[k * 64 + lane];
    float asl = a_s[lane], adl = a_d[lane];

    for (int n = wid; n < NN; n += nwaves_total) {
        int nu = __builtin_amdgcn_readfirstlane(n);
        const float* xrow = x + (size_t)nu * FD;
        float acc = 0.f;
#pragma unroll
        for (int k = 0; k < FD; ++k) acc = fmaf(xrow[k], wcol[k], acc);
        h[(size_t)nu * 64 + lane] = __float2half(acc);
        float vs = acc * asl;
        float vd = acc * adl;
        for (int w = 32; w >= 1; w >>= 1) {
            vs += __shfl_xor(vs, w);
            vd += __shfl_xor(vd, w);
        }
        if (lane == 0) { es[nu] = vs; ed[nu] = vd; }
    }
}

// Hidden/final projection as MFMA GEMM (R13, verified): one wave = 16x64 stripe,
// 8x mfma_f32_16x16x32_f16. es/ed folded via per-tile scale + 16-lane butterfly.
__global__ void k_hc_mfma(const __half* __restrict__ X,
                          const __half* __restrict__ wpack,   // this layer's 8 frags
                          const float* __restrict__ a_s, const float* __restrict__ a_d,
                          __half* __restrict__ H, float* __restrict__ es,
                          float* __restrict__ ed) {
    int lane = threadIdx.x & 63;
    int stripe = (blockIdx.x * blockDim.x + threadIdx.x) >> 6;
    if (stripe >= STRIPES) return;
    int rowbase = stripe * 16;
    int lr = lane & 15, lg = lane >> 4;

    f16x8 b[8];
    const float4* wp = (const float4*)wpack;
#pragma unroll
    for (int f = 0; f < 8; ++f) {
        float4 raw = wp[f * 64 + lane];
        b[f] = *(const f16x8*)&raw;
    }
    const __half* xrow = X + (size_t)(rowbase + lr) * 64 + lg * 8;
    float4 a0raw = *(const float4*)xrow;
    float4 a1raw = *(const float4*)(xrow + 32);
    f16x8 a0 = *(const f16x8*)&a0raw;
    f16x8 a1 = *(const f16x8*)&a1raw;

    float esa[4] = {0.f, 0.f, 0.f, 0.f};
    float eda[4] = {0.f, 0.f, 0.f, 0.f};
#pragma unroll
    for (int t = 0; t < 4; ++t) {
        f32x4 acc = {0.f, 0.f, 0.f, 0.f};
        acc = __builtin_amdgcn_mfma_f32_16x16x32_f16(a0, b[t * 2], acc, 0, 0, 0);
        acc = __builtin_amdgcn_mfma_f32_16x16x32_f16(a1, b[t * 2 + 1], acc, 0, 0, 0);
        float asv = a_s[t * 16 + lr];
        float adv = a_d[t * 16 + lr];
#pragma unroll
        for (int r = 0; r < 4; ++r) {
            float v = acc[r];
            H[(size_t)(rowbase + lg * 4 + r) * 64 + t * 16 + lr] = __float2half(v);
            esa[r] = fmaf(v, asv, esa[r]);
            eda[r] = fmaf(v, adv, eda[r]);
        }
    }
#pragma unroll
    for (int w = 1; w <= 8; w <<= 1) {
#pragma unroll
        for (int r = 0; r < 4; ++r) {
            esa[r] += __shfl_xor(esa[r], w);
            eda[r] += __shfl_xor(eda[r], w);
        }
    }
    if (lr == 0) {
#pragma unroll
        for (int r = 0; r < 4; ++r) {
            es[rowbase + lg * 4 + r] = esa[r];
            ed[rowbase + lg * 4 + r] = eda[r];
        }
    }
}

// One wave per dst node, single fused pass (R14, best-known). Phase-split per
// 64-edge chunk: phase A computes p edge-per-lane (one es-gather + one exp per
// edge); phase B redistributes p/sj via __shfl and gathers 16 edges/sub-iter
// with 2 independent 16B row loads per lane. Aggregate is L2-miss-BW bound
// (FETCH ~= 8 XCDs x table, ~2TB/s random-fetch path) -- measured floor.
template<int HIDDEN>
__global__ void k_aggregate(const __half* __restrict__ h,
                            const float* __restrict__ es, const float* __restrict__ ed,
                            const int* __restrict__ offsets, const int* __restrict__ ssrc,
                            const float* __restrict__ bias,
                            __half* __restrict__ outH, float* __restrict__ outF) {
    int gtid = blockIdx.x * blockDim.x + threadIdx.x;
    int n = gtid >> 6;
    int lane = threadIdx.x & 63;
    if (n >= NN) return;
    int beg = offsets[n], end = offsets[n + 1];
    float ednv = ed[n];

    int grp = lane >> 3;        // 0..7 : which edge of the group
    int c   = lane & 7;         // channel block: halves [8c, 8c+8)
    float s = 0.f;
    float acc[8];
#pragma unroll
    for (int i = 0; i < 8; ++i) acc[i] = 0.f;

    for (int j0 = beg; j0 < end; j0 += 64) {
        // phase A: edge-per-lane p
        int j = j0 + lane;
        float p = 0.f;
        int sjA = 0;
        if (j < end) {
            sjA = ssrc[j];
            float e = es[sjA] + ednv;
            e = (e > 0.f) ? e : NEG_SLOPE * e;
            p = __expf(e);
        }
        s += p;
        int cnt = end - j0; if (cnt > 64) cnt = 64;
        // phase B: 16 edges per sub-iter, 2 gathers in flight per lane
        for (int sub = 0; sub * 16 < cnt; ++sub) {
            int e0 = sub * 16 + grp;
            int e1 = sub * 16 + 8 + grp;
            float pe0 = __shfl(p, e0);
            float pe1 = __shfl(p, e1);
            int sj0 = __shfl(sjA, e0);
            int sj1 = __shfl(sjA, e1);
            float4 raw0 = *(const float4*)&h[(size_t)sj0 * 64 + c * 8];
            float4 raw1 = *(const float4*)&h[(size_t)sj1 * 64 + c * 8];
            const __half2* hp0 = (const __half2*)&raw0;
#pragma unroll
            for (int q = 0; q < 4; ++q) {
                float2 f = __half22float2(hp0[q]);
                acc[2 * q]     = fmaf(pe0, f.x, acc[2 * q]);
                acc[2 * q + 1] = fmaf(pe0, f.y, acc[2 * q + 1]);
            }
            const __half2* hp1 = (const __half2*)&raw1;
#pragma unroll
            for (int q = 0; q < 4; ++q) {
                float2 f = __half22float2(hp1[q]);
                acc[2 * q]     = fmaf(pe1, f.x, acc[2 * q]);
                acc[2 * q + 1] = fmaf(pe1, f.y, acc[2 * q + 1]);
            }
        }
    }
    // s: full 64-lane butterfly; acc: reduce across the 8 edge-groups
#pragma unroll
    for (int w = 32; w >= 1; w >>= 1) s += __shfl_xor(s, w);
#pragma unroll
    for (int w = 8; w <= 32; w <<= 1) {
#pragma unroll
        for (int i = 0; i < 8; ++i) acc[i] += __shfl_xor(acc[i], w);
    }
    if (grp == 0) {
        float inv_s = 1.0f / s;
        float v[8];
#pragma unroll
        for (int i = 0; i < 8; ++i) {
            v[i] = acc[i] * inv_s + bias[c * 8 + i];
            if (HIDDEN) v[i] = fmaxf(v[i], 0.f);
        }
        if (HIDDEN) {
            __half2 hv[4];
#pragma unroll
            for (int q = 0; q < 4; ++q)
                hv[q] = __floats2half2_rn(v[2 * q], v[2 * q + 1]);
            *(float4*)&outH[(size_t)n * 64 + c * 8] = *(float4*)hv;   // 16B
        } else {
            *(float4*)&outF[(size_t)n * 64 + c * 8]     = make_float4(v[0], v[1], v[2], v[3]);
            *(float4*)&outF[(size_t)n * 64 + c * 8 + 4] = make_float4(v[4], v[5], v[6], v[7]);
        }
    }
}

// ---------------- epilogue ----------------

__global__ void k_pool1(const float* __restrict__ h, float* __restrict__ partial) {
    int blk = blockIdx.x;
    int g = blk / POOL_CHUNKS, c = blk % POOL_CHUNKS;
    int wave = threadIdx.x >> 6, lane = threadIdx.x & 63;
    int base = g * NODES_PER_GRAPH + c * POOL_NODES_PER_CHUNK;
    float acc = 0.f;
    for (int i = wave; i < POOL_NODES_PER_CHUNK; i += 4)
        acc += h[(size_t)(base + i) * 64 + lane];
    __shared__ float buf[4][64];
    buf[wave][lane] = acc;
    __syncthreads();
    if (wave == 0)
        partial[blk * 64 + lane] = buf[0][lane] + buf[1][lane] + buf[2][lane] + buf[3][lane];
}

// fused pool-stage-2 + value head: 10 blocks x 512 threads.
__global__ void k_pool2_value(const float* __restrict__ partial,
                              const float* __restrict__ Wv1, const float* __restrict__ bv1,
                              const float* __restrict__ Wv2, const float* __restrict__ bv2,
                              float* __restrict__ pooled, float* __restrict__ value) {
    int g = blockIdx.x;
    int j = threadIdx.x;   // 512
    __shared__ float pl[64];
    if (j < 64) {
        float a = 0.f;
        for (int cc = 0; cc < POOL_CHUNKS; ++cc)
            a += partial[(g * POOL_CHUNKS + cc) * 64 + j];
        a *= (1.0f / NODES_PER_GRAPH);
        pooled[g * 64 + j] = a;
        pl[j] = a;
    }
    __syncthreads();
    float acc = bv1[j];
    for (int cc = 0; cc < 64; ++cc) acc += pl[cc] * Wv1[cc * 512 + j];
    acc = fmaxf(acc, 0.f);
    float t = acc * Wv2[j];
    for (int w = 32; w >= 1; w >>= 1) t += __shfl_xor(t, w);
    __shared__ float red[8];
    int wave = j >> 6, lane = j & 63;
    if (lane == 0) red[wave] = t;
    __syncthreads();
    if (j == 0) {
        float v = 0.f;
        for (int w = 0; w < 8; ++w) v += red[w];
        value[g] = v + bv2[0];
    }
}

// ---------------- launcher ----------------

extern "C" void kernel_launch(void* const* d_in, const int* in_sizes, int n_in,
                              void* d_out, int out_size, void* d_ws, size_t ws_size,
                              hipStream_t stream) {
    const float* x   = (const float*)d_in[0];
    const int*   ei  = (const int*)d_in[1];     // (2, E): row0=src, row1=dst
    const float* W1  = (const float*)d_in[2];
    const float* as1 = (const float*)d_in[3];
    const float* ad1 = (const float*)d_in[4];
    const float* b1  = (const float*)d_in[5];
    const float* Wh  = (const float*)d_in[6];   // (2,64,64)
    const float* ash = (const float*)d_in[7];
    const float* adh = (const float*)d_in[8];
    const float* bh  = (const float*)d_in[9];
    const float* W2  = (const float*)d_in[10];
    const float* as2 = (const float*)d_in[11];
    const float* ad2 = (const float*)d_in[12];
    const float* b2  = (const float*)d_in[13];
    const float* Wv1 = (const float*)d_in[14];
    const float* bv1 = (const float*)d_in[15];
    const float* Wv2 = (const float*)d_in[16];
    const float* bv2 = (const float*)d_in[17];

    const int* e_src = ei;
    const int* e_dst = ei + EE;

    // workspace carve-up (256B aligned)
    char* p = (char*)d_ws;
    auto carve = [&](size_t bytes) {
        char* r = p;
        p += (bytes + 255) & ~(size_t)255;
        return r;
    };
    int*    counts    = (int*)carve(NN * 4);
    int*    offsets   = (int*)carve((NN + 1) * 4);
    int*    cursors   = (int*)carve(NN * 4);
    int*    ssrc      = (int*)carve(TOT_EDGES * 4);
    int*    blocksums = (int*)carve(SCAN_GRID * 4);
    __half* wpack     = (__half*)carve(3 * 8 * 64 * 8 * 2);    // packed W fragments
    __half* bufH      = (__half*)carve((size_t)NN * 64 * 2);   // fp16 gather table
    __half* bufB16    = (__half*)carve((size_t)NN * 64 * 2);   // fp16 layer boundary
    float*  es        = (float*)carve(NN * 4);
    float*  ed        = (float*)carve(NN * 4);
    float*  partial   = (float*)carve((size_t)NUM_GRAPHS * POOL_CHUNKS * 64 * 4);

    float* out_h      = (float*)d_out;                 // [N, 64]
    float* out_pooled = out_h + (size_t)NN * 64;       // [10, 64]
    float* out_value  = out_pooled + NUM_GRAPHS * 64;  // [10]

    // CSR build (reused by all 4 layers) + W packing
    hipMemsetAsync(counts, 0, NN * 4, stream);
    k_count_part<<<NPART * CSR_CHUNKS, 256, 0, stream>>>(e_dst, counts);
    k_scan1<<<SCAN_GRID, SCAN_BLK, 0, stream>>>(counts, offsets, blocksums);
    k_scan2<<<1, 64, 0, stream>>>(blocksums, offsets);
    k_scan3<<<SCAN_GRID, SCAN_BLK, 0, stream>>>(offsets, cursors, blocksums);
    k_scatter_part<<<NPART * CSR_CHUNKS, 256, 0, stream>>>(e_src, e_dst, cursors, ssrc);
    k_wpack<<<6, 256, 0, stream>>>(Wh, W2, wpack);

    const int HBLK = (NN + 3) / 4;             // aggregate: 4 waves/block, 1 node/wave
    const int HC_WAVES = HC_BLOCKS * 256 / 64; // 4096
    const int WPL = 8 * 64 * 8;                // wpack halves per layer

    // layer 1: FD -> C (scalar), relu; boundary buffer is fp16
    k_hcompute_f3<<<HC_BLOCKS, 256, 0, stream>>>(x, W1, as1, ad1, bufH, es, ed, HC_WAVES);
    k_aggregate<1><<<HBLK, 256, 0, stream>>>(bufH, es, ed, offsets, ssrc, b1, bufB16, nullptr);

    // hidden layers: C -> C via MFMA, relu in aggregate
    for (int i = 0; i < 2; ++i) {
        k_hc_mfma<<<MFMA_BLOCKS, 256, 0, stream>>>(bufB16, wpack + i * WPL,
                                                   ash + i * 64, adh + i * 64,
                                                   bufH, es, ed);
        k_aggregate<1><<<HBLK, 256, 0, stream>>>(bufH, es, ed, offsets, ssrc, bh + i * 64,
                                                 bufB16, nullptr);
    }

    // layer 4: C -> OUT via MFMA, no relu, write straight to d_out (fp32)
    k_hc_mfma<<<MFMA_BLOCKS, 256, 0, stream>>>(bufB16, wpack + 2 * WPL, as2, ad2,
                                               bufH, es, ed);
    k_aggregate<0><<<HBLK, 256, 0, stream>>>(bufH, es, ed, offsets, ssrc, b2, nullptr, out_h);

    // pooling + value head
    k_pool1<<<NUM_GRAPHS * POOL_CHUNKS, 256, 0, stream>>>(out_h, partial);
    k_pool2_value<<<NUM_GRAPHS, 512, 0, stream>>>(partial, Wv1, bv1, Wv2, bv2,
                                                  out_pooled, out_value);
}